// Round 1
// baseline (2884.796 us; speedup 1.0000x reference)
//
#include <hip/hip_runtime.h>

// ---------------- helpers ----------------
__device__ __forceinline__ float bf_lo(unsigned u){ return __uint_as_float(u << 16); }
__device__ __forceinline__ float bf_hi(unsigned u){ return __uint_as_float(u & 0xffff0000u); }
__device__ __forceinline__ unsigned short f2bf(float f){
  unsigned u = __float_as_uint(f);
  u += 0x7fffu + ((u >> 16) & 1u);   // RNE
  return (unsigned short)(u >> 16);
}
__device__ __forceinline__ unsigned pk2(float a, float b){
  return (unsigned)f2bf(a) | ((unsigned)f2bf(b) << 16);
}

// ---------------- kernel 1: LayerNorm over d_m + transpose msa[c][n][l] -> x[l][n][c] (bf16) ----------------
__global__ __launch_bounds__(256) void ln_msa_kernel(
    const float* __restrict__ msa, const float* __restrict__ gam,
    const float* __restrict__ bet, unsigned short* __restrict__ x16)
{
  __shared__ float tile[256*33];          // [c][l] pitch 33
  __shared__ float ps[8*32], pq[8*32];
  __shared__ float mean_s[32], rstd_s[32];
  const int t = threadIdx.x;
  const int l0 = blockIdx.x * 32;
  const int n  = blockIdx.y;
  {
    const int lt = t & 31, ct = t >> 5;   // ct 0..7
    for (int r = 0; r < 32; ++r) {
      int c = r*8 + ct;
      tile[c*33 + lt] = msa[(size_t)c*131072 + (size_t)n*1024 + l0 + lt];
    }
  }
  __syncthreads();
  {
    const int lt = t & 31, cp = t >> 5;
    float s1 = 0.f, s2 = 0.f;
    for (int cc = 0; cc < 32; ++cc) {
      int c = cp*32 + ((cc + cp*4) & 31);  // stagger to avoid bank conflicts
      float v = tile[c*33 + lt];
      s1 += v; s2 += v*v;
    }
    ps[cp*32 + lt] = s1; pq[cp*32 + lt] = s2;
  }
  __syncthreads();
  if (t < 32) {
    float s1 = 0.f, s2 = 0.f;
    for (int cp = 0; cp < 8; ++cp){ s1 += ps[cp*32+t]; s2 += pq[cp*32+t]; }
    float m = s1 * (1.f/256.f);
    float v = s2 * (1.f/256.f) - m*m;
    mean_s[t] = m;
    rstd_s[t] = rsqrtf(v + 1e-5f);
  }
  __syncthreads();
  {
    const float g = gam[t], b = bet[t];
    for (int l = 0; l < 32; ++l) {
      float v = (tile[t*33 + l] - mean_s[l]) * rstd_s[l] * g + b;
      x16[((size_t)(l0+l)*128 + n)*256 + t] = f2bf(v);
    }
  }
}

// ---------------- kernel 2: pair bias = LN(pairs) @ Wb -> bias[h][i][j] fp32 ----------------
__global__ __launch_bounds__(64) void pair_bias_kernel(
    const float* __restrict__ pairs, const float* __restrict__ gam,
    const float* __restrict__ bet, const float* __restrict__ Wb,
    float* __restrict__ biasb)
{
  const int j = blockIdx.x, i = blockIdx.y;
  const int t = threadIdx.x;                    // one wave
  const float* row = pairs + ((size_t)i*128 + j)*128;
  float v0 = row[t], v1 = row[t+64];
  float s = v0 + v1;
  #pragma unroll
  for (int o = 1; o < 64; o <<= 1) s += __shfl_xor(s, o, 64);
  float m = s * (1.f/128.f);
  float d0 = v0 - m, d1 = v1 - m;
  float q = d0*d0 + d1*d1;
  #pragma unroll
  for (int o = 1; o < 64; o <<= 1) q += __shfl_xor(q, o, 64);
  float rstd = rsqrtf(q * (1.f/128.f) + 1e-5f);
  float n0 = d0 * rstd * gam[t]    + bet[t];
  float n1 = d1 * rstd * gam[t+64] + bet[t+64];
  #pragma unroll
  for (int h = 0; h < 8; ++h) {
    float p = n0 * Wb[t*8 + h] + n1 * Wb[(t+64)*8 + h];
    #pragma unroll
    for (int o = 1; o < 64; o <<= 1) p += __shfl_xor(p, o, 64);
    if (t == h) biasb[((size_t)h*128 + i)*128 + j] = p;
  }
}

// ---------------- kernel 3: fused per-l attention ----------------
// block = one l, 512 threads. LDS q/k/v/g bf16 [128 rows][pitch 40].
// stage1: waves 0-1 -> q, 2-3 -> k, 4-5 -> v, 6-7 -> g; each thread 4 rows x 8 dims.
// stage2: thread (i = t>>2, jg = t&3): scores for 32 j's, softmax, PV, gate.
// Output written in-place over x buffer (register-buffered until after last barrier).
__global__ __launch_bounds__(512) void attn_fused_kernel(
    unsigned short* xbuf,
    const float* __restrict__ Wq, const float* __restrict__ Wk,
    const float* __restrict__ Wv, const float* __restrict__ Wg,
    const float* __restrict__ bg, const float* __restrict__ biasb)
{
  __shared__ unsigned short qs[128*40], ks[128*40], vs[128*40], gs[128*40];
  const int t = threadIdx.x;
  const int l = blockIdx.x;
  // stage1 mapping
  const int mat = t >> 7;
  const int tt  = t & 127;
  const int dg  = tt >> 5;      // 0..3 -> d = dg*8..+7
  const int i4  = tt & 31;      // rows i4*4..+3
  const float* Wmat = (mat==0) ? Wq : (mat==1) ? Wk : (mat==2) ? Wv : Wg;
  unsigned short* outs = (mat==0) ? qs : (mat==1) ? ks : (mat==2) ? vs : gs;
  const uint4* xr = (const uint4*)(xbuf + ((size_t)l*128 + (size_t)i4*4)*256);
  // stage2 mapping
  const int i  = t >> 2;
  const int jg = t & 3;
  const int lane = t & 63;
  uint4 outv[8];
  const float inv_sqrt = 0.17677669529663689f;  // 1/sqrt(32)

  for (int h = 0; h < 8; ++h) {
    // ---- stage 1: projections for head h ----
    {
      const int co = h*32 + dg*8;
      float acc[4][8];
      #pragma unroll
      for (int r=0;r<4;++r){
        #pragma unroll
        for (int u=0;u<8;++u) acc[r][u]=0.f;
      }
      for (int cb = 0; cb < 32; ++cb) {
        uint4 xv[4];
        #pragma unroll
        for (int r=0;r<4;++r) xv[r] = xr[r*32 + cb];
        #pragma unroll
        for (int u=0;u<8;++u) {
          const float4* wp = (const float4*)(Wmat + ((size_t)(cb*8+u))*256 + co);
          float4 w0 = wp[0], w1 = wp[1];
          #pragma unroll
          for (int r=0;r<4;++r) {
            unsigned word = (u<4) ? ((u<2)? xv[r].x : xv[r].y) : ((u<6)? xv[r].z : xv[r].w);
            float xf = (u&1) ? bf_hi(word) : bf_lo(word);
            acc[r][0] += xf*w0.x; acc[r][1] += xf*w0.y;
            acc[r][2] += xf*w0.z; acc[r][3] += xf*w0.w;
            acc[r][4] += xf*w1.x; acc[r][5] += xf*w1.y;
            acc[r][6] += xf*w1.z; acc[r][7] += xf*w1.w;
          }
        }
      }
      #pragma unroll
      for (int r=0;r<4;++r) {
        float vv[8];
        #pragma unroll
        for (int u=0;u<8;++u) vv[u] = acc[r][u];
        if (mat == 0) {
          #pragma unroll
          for (int u=0;u<8;++u) vv[u] *= inv_sqrt;
        }
        if (mat == 3) {
          #pragma unroll
          for (int u=0;u<8;++u) vv[u] = 1.f/(1.f + __expf(-(vv[u] + bg[co+u])));
        }
        uint4 pkd;
        pkd.x = pk2(vv[0],vv[1]); pkd.y = pk2(vv[2],vv[3]);
        pkd.z = pk2(vv[4],vv[5]); pkd.w = pk2(vv[6],vv[7]);
        *(uint4*)(outs + (size_t)(i4*4+r)*40 + dg*8) = pkd;
      }
    }
    __syncthreads();
    // ---- stage 2: scores + softmax + PV + gate ----
    {
      float qrf[32];
      const uint4* qrow = (const uint4*)(qs + (size_t)i*40);
      #pragma unroll
      for (int d4=0; d4<4; ++d4) {
        uint4 qw = qrow[d4];
        qrf[d4*8+0]=bf_lo(qw.x); qrf[d4*8+1]=bf_hi(qw.x);
        qrf[d4*8+2]=bf_lo(qw.y); qrf[d4*8+3]=bf_hi(qw.y);
        qrf[d4*8+4]=bf_lo(qw.z); qrf[d4*8+5]=bf_hi(qw.z);
        qrf[d4*8+6]=bf_lo(qw.w); qrf[d4*8+7]=bf_hi(qw.w);
      }
      const float* brow = biasb + ((size_t)h*128 + i)*128;
      float sm[32];
      #pragma unroll
      for (int m=0;m<32;++m) {
        int j = m*4 + jg;
        const uint4* kr = (const uint4*)(ks + (size_t)j*40);
        float s = brow[j];
        #pragma unroll
        for (int d4=0;d4<4;++d4) {
          uint4 kw = kr[d4];
          s += qrf[d4*8+0]*bf_lo(kw.x) + qrf[d4*8+1]*bf_hi(kw.x)
             + qrf[d4*8+2]*bf_lo(kw.y) + qrf[d4*8+3]*bf_hi(kw.y)
             + qrf[d4*8+4]*bf_lo(kw.z) + qrf[d4*8+5]*bf_hi(kw.z)
             + qrf[d4*8+6]*bf_lo(kw.w) + qrf[d4*8+7]*bf_hi(kw.w);
        }
        sm[m] = s;
      }
      float mx = sm[0];
      #pragma unroll
      for (int m=1;m<32;++m) mx = fmaxf(mx, sm[m]);
      mx = fmaxf(mx, __shfl_xor(mx, 1, 64));
      mx = fmaxf(mx, __shfl_xor(mx, 2, 64));
      float sum = 0.f;
      #pragma unroll
      for (int m=0;m<32;++m) { sm[m] = __expf(sm[m]-mx); sum += sm[m]; }
      sum += __shfl_xor(sum, 1, 64);
      sum += __shfl_xor(sum, 2, 64);
      float inv = 1.f / sum;
      #pragma unroll
      for (int m=0;m<32;++m) sm[m] *= inv;   // sm now = softmax weights for j = m*4+jg
      // PV: each lane accumulates only its own d-slice (jg*8..+7) over ALL j,
      // broadcasting w from the lane that owns j via shfl.
      float o[8];
      #pragma unroll
      for (int u=0;u<8;++u) o[u]=0.f;
      #pragma unroll
      for (int mm=0; mm<128; ++mm) {
        float w = __shfl(sm[mm>>2], (lane & ~3) | (mm & 3), 64);
        const uint4* vr = (const uint4*)(vs + (size_t)mm*40 + jg*8);
        uint4 vw = *vr;
        o[0] += w*bf_lo(vw.x); o[1] += w*bf_hi(vw.x);
        o[2] += w*bf_lo(vw.y); o[3] += w*bf_hi(vw.y);
        o[4] += w*bf_lo(vw.z); o[5] += w*bf_hi(vw.z);
        o[6] += w*bf_lo(vw.w); o[7] += w*bf_hi(vw.w);
      }
      const uint4* grow = (const uint4*)(gs + (size_t)i*40 + jg*8);
      uint4 gw = *grow;
      uint4 pkd;
      pkd.x = pk2(bf_lo(gw.x)*o[0], bf_hi(gw.x)*o[1]);
      pkd.y = pk2(bf_lo(gw.y)*o[2], bf_hi(gw.y)*o[3]);
      pkd.z = pk2(bf_lo(gw.z)*o[4], bf_hi(gw.z)*o[5]);
      pkd.w = pk2(bf_lo(gw.w)*o[6], bf_hi(gw.w)*o[7]);
      outv[h] = pkd;
    }
    __syncthreads();
  }
  // final in-place writes (no thread reads xbuf after the last barrier)
  unsigned short* dst = xbuf + ((size_t)l*128 + i)*256 + jg*8;
  #pragma unroll
  for (int h=0;h<8;++h) *(uint4*)(dst + h*32) = outv[h];
}

// ---------------- kernel 4: out = attn @ Wo + bo, written transposed to [d_m][n][L] ----------------
__global__ __launch_bounds__(256) void outproj_kernel(
    const unsigned short* __restrict__ attn16, const float* __restrict__ Wo,
    const float* __restrict__ bo, float* __restrict__ out)
{
  __shared__ float As[16*68];  // [k][l-row] pitch 68
  __shared__ float Bs[16*68];  // [k][c]     pitch 68
  const int t  = threadIdx.x;
  const int l0 = blockIdx.x * 64;
  const int c0 = blockIdx.y * 64;
  const int iz = blockIdx.z;      // n index
  const int tx = t & 15, ty = t >> 4;
  float acc[4][4];
  #pragma unroll
  for (int a=0;a<4;++a){
    #pragma unroll
    for (int b=0;b<4;++b) acc[a][b]=0.f;
  }
  for (int kc = 0; kc < 256; kc += 16) {
    if (kc) __syncthreads();
    {
      // A: 64 rows (l) x 16 k, bf16 -> fp32, stored transposed As[k][r]
      const int r = t >> 2, kq = (t & 3)*4;
      const unsigned short* src = attn16 + ((size_t)(l0+r)*128 + iz)*256 + kc + kq;
      uint2 u2 = *(const uint2*)src;
      As[(kq+0)*68 + r] = bf_lo(u2.x);
      As[(kq+1)*68 + r] = bf_hi(u2.x);
      As[(kq+2)*68 + r] = bf_lo(u2.y);
      As[(kq+3)*68 + r] = bf_hi(u2.y);
      // B: 16 k x 64 c
      const int kk = t >> 4, cq = (t & 15)*4;
      float4 wv = *(const float4*)(Wo + (size_t)(kc+kk)*256 + c0 + cq);
      *(float4*)&Bs[kk*68 + cq] = wv;
    }
    __syncthreads();
    #pragma unroll
    for (int kk=0; kk<16; ++kk) {
      float4 av = *(const float4*)&As[kk*68 + ty*4];
      float4 bv = *(const float4*)&Bs[kk*68 + tx*4];
      acc[0][0]+=av.x*bv.x; acc[0][1]+=av.x*bv.y; acc[0][2]+=av.x*bv.z; acc[0][3]+=av.x*bv.w;
      acc[1][0]+=av.y*bv.x; acc[1][1]+=av.y*bv.y; acc[1][2]+=av.y*bv.z; acc[1][3]+=av.y*bv.w;
      acc[2][0]+=av.z*bv.x; acc[2][1]+=av.z*bv.y; acc[2][2]+=av.z*bv.z; acc[2][3]+=av.z*bv.w;
      acc[3][0]+=av.w*bv.x; acc[3][1]+=av.w*bv.y; acc[3][2]+=av.w*bv.z; acc[3][3]+=av.w*bv.w;
    }
  }
  #pragma unroll
  for (int uc=0; uc<4; ++uc) {
    const int c = c0 + tx*4 + uc;
    const float bv = bo[c];
    float4 res;
    res.x = acc[0][uc] + bv;
    res.y = acc[1][uc] + bv;
    res.z = acc[2][uc] + bv;
    res.w = acc[3][uc] + bv;
    *(float4*)(out + (size_t)c*131072 + (size_t)iz*1024 + l0 + ty*4) = res;
  }
}

// ---------------- launch ----------------
extern "C" void kernel_launch(void* const* d_in, const int* in_sizes, int n_in,
                              void* d_out, int out_size, void* d_ws, size_t ws_size,
                              hipStream_t stream) {
  const float* msa    = (const float*)d_in[0];
  const float* pairs  = (const float*)d_in[1];
  const float* ln_m_g = (const float*)d_in[2];
  const float* ln_m_b = (const float*)d_in[3];
  const float* ln_p_g = (const float*)d_in[4];
  const float* ln_p_b = (const float*)d_in[5];
  const float* Wq     = (const float*)d_in[6];
  const float* Wk     = (const float*)d_in[7];
  const float* Wv     = (const float*)d_in[8];
  const float* Wg     = (const float*)d_in[9];
  const float* bg     = (const float*)d_in[10];
  const float* Wb     = (const float*)d_in[11];
  const float* Wo     = (const float*)d_in[12];
  const float* bo     = (const float*)d_in[13];
  float* out = (float*)d_out;

  unsigned short* x16 = (unsigned short*)d_ws;                 // 64 MiB: x, then attn in-place
  float* biasb = (float*)((char*)d_ws + (size_t)67108864);     // 512 KiB: [8][128][128]

  hipLaunchKernelGGL(ln_msa_kernel, dim3(32,128), dim3(256), 0, stream,
                     msa, ln_m_g, ln_m_b, x16);
  hipLaunchKernelGGL(pair_bias_kernel, dim3(128,128), dim3(64), 0, stream,
                     pairs, ln_p_g, ln_p_b, Wb, biasb);
  hipLaunchKernelGGL(attn_fused_kernel, dim3(1024), dim3(512), 0, stream,
                     x16, Wq, Wk, Wv, Wg, bg, biasb);
  hipLaunchKernelGGL(outproj_kernel, dim3(16,4,128), dim3(256), 0, stream,
                     x16, Wo, bo, out);
}

// Round 2
// 787.613 us; speedup vs baseline: 3.6627x; 3.6627x over previous
//
#include <hip/hip_runtime.h>

// ---------------- helpers ----------------
__device__ __forceinline__ float bf_lo(unsigned u){ return __uint_as_float(u << 16); }
__device__ __forceinline__ float bf_hi(unsigned u){ return __uint_as_float(u & 0xffff0000u); }
__device__ __forceinline__ float bf1(unsigned short s){ return __uint_as_float((unsigned)s << 16); }
__device__ __forceinline__ unsigned short f2bf(float f){
  unsigned u = __float_as_uint(f);
  u += 0x7fffu + ((u >> 16) & 1u);   // RNE
  return (unsigned short)(u >> 16);
}

typedef __attribute__((ext_vector_type(8))) short short8;
typedef __attribute__((ext_vector_type(4))) float f32x4;

__device__ __forceinline__ f32x4 mfma16(short8 a, short8 b, f32x4 c){
  return __builtin_amdgcn_mfma_f32_16x16x32_bf16(a, b, c, 0, 0, 0);
}

#define GLOAD_LDS16(g, l) \
  __builtin_amdgcn_global_load_lds((const __attribute__((address_space(1))) unsigned int*)(g), \
                                   (__attribute__((address_space(3))) unsigned int*)(l), 16, 0, 0)

// ---------------- kernel 1: LayerNorm over d_m + transpose msa[c][n][l] -> x[l][n][c] (bf16) ----------------
__global__ __launch_bounds__(256) void ln_msa_kernel(
    const float* __restrict__ msa, const float* __restrict__ gam,
    const float* __restrict__ bet, unsigned short* __restrict__ x16)
{
  __shared__ float tile[256*33];          // [c][l] pitch 33
  __shared__ float ps[8*32], pq[8*32];
  __shared__ float mean_s[32], rstd_s[32];
  const int t = threadIdx.x;
  const int l0 = blockIdx.x * 32;
  const int n  = blockIdx.y;
  {
    const int lt = t & 31, ct = t >> 5;
    for (int r = 0; r < 32; ++r) {
      int c = r*8 + ct;
      tile[c*33 + lt] = msa[(size_t)c*131072 + (size_t)n*1024 + l0 + lt];
    }
  }
  __syncthreads();
  {
    const int lt = t & 31, cp = t >> 5;
    float s1 = 0.f, s2 = 0.f;
    for (int cc = 0; cc < 32; ++cc) {
      int c = cp*32 + ((cc + cp*4) & 31);
      float v = tile[c*33 + lt];
      s1 += v; s2 += v*v;
    }
    ps[cp*32 + lt] = s1; pq[cp*32 + lt] = s2;
  }
  __syncthreads();
  if (t < 32) {
    float s1 = 0.f, s2 = 0.f;
    for (int cp = 0; cp < 8; ++cp){ s1 += ps[cp*32+t]; s2 += pq[cp*32+t]; }
    float m = s1 * (1.f/256.f);
    float v = s2 * (1.f/256.f) - m*m;
    mean_s[t] = m;
    rstd_s[t] = rsqrtf(v + 1e-5f);
  }
  __syncthreads();
  {
    const float g = gam[t], b = bet[t];
    for (int l = 0; l < 32; ++l) {
      float v = (tile[t*33 + l] - mean_s[l]) * rstd_s[l] * g + b;
      x16[((size_t)(l0+l)*128 + n)*256 + t] = f2bf(v);
    }
  }
}

// ---------------- kernel 2: pair bias = LN(pairs) @ Wb -> bias[h][i][j] fp32 ----------------
__global__ __launch_bounds__(64) void pair_bias_kernel(
    const float* __restrict__ pairs, const float* __restrict__ gam,
    const float* __restrict__ bet, const float* __restrict__ Wb,
    float* __restrict__ biasb)
{
  const int j = blockIdx.x, i = blockIdx.y;
  const int t = threadIdx.x;
  const float* row = pairs + ((size_t)i*128 + j)*128;
  float v0 = row[t], v1 = row[t+64];
  float s = v0 + v1;
  #pragma unroll
  for (int o = 1; o < 64; o <<= 1) s += __shfl_xor(s, o, 64);
  float m = s * (1.f/128.f);
  float d0 = v0 - m, d1 = v1 - m;
  float q = d0*d0 + d1*d1;
  #pragma unroll
  for (int o = 1; o < 64; o <<= 1) q += __shfl_xor(q, o, 64);
  float rstd = rsqrtf(q * (1.f/128.f) + 1e-5f);
  float n0 = d0 * rstd * gam[t]    + bet[t];
  float n1 = d1 * rstd * gam[t+64] + bet[t+64];
  #pragma unroll
  for (int h = 0; h < 8; ++h) {
    float p = n0 * Wb[t*8 + h] + n1 * Wb[(t+64)*8 + h];
    #pragma unroll
    for (int o = 1; o < 64; o <<= 1) p += __shfl_xor(p, o, 64);
    if (t == h) biasb[((size_t)h*128 + i)*128 + j] = p;
  }
}

// ---------------- kernel 3: weight prep: Wt[n=1024][k=256] = W_mat[k][n&255] bf16, q scaled ----------------
__global__ __launch_bounds__(256) void wprep_kernel(
    const float* __restrict__ Wq, const float* __restrict__ Wk,
    const float* __restrict__ Wv, const float* __restrict__ Wg,
    unsigned short* __restrict__ Wt)
{
  const int n = blockIdx.x, k = threadIdx.x;
  const int mat = n >> 8, nl = n & 255;
  const float* W = (mat==0) ? Wq : (mat==1) ? Wk : (mat==2) ? Wv : Wg;
  float v = W[(size_t)k*256 + nl];
  if (mat == 0) v *= 0.17677669529663689f;   // 1/sqrt(32) folded into Wq
  Wt[(size_t)n*256 + k] = f2bf(v);
}

// ---------------- kernel 4: MFMA GEMM: [Q|K|V|G] = X @ Wt^T ----------------
// X[131072][256] bf16, Wt[1024][256] bf16 (B^T layout).
// Q/K/G -> qkg[(mat'*8+h)][m][32] bf16 (mat' = 0:q,1:k,2:g); sigmoid fused for G.
// V -> vT[h][l][d=32][chunk-swizzled 128] bf16 (transposed per l-tile).
__global__ __launch_bounds__(256) void qkvg_gemm(
    const unsigned short* __restrict__ X, const unsigned short* __restrict__ Wt,
    const float* __restrict__ bg, unsigned short* __restrict__ qkg,
    unsigned short* __restrict__ vT)
{
  __shared__ __align__(16) unsigned short As[128*64], Bs[128*64];
  const int t = threadIdx.x;
  const int m0 = blockIdx.x*128, n0 = blockIdx.y*128;
  const int w = t>>6, lane = t&63, fr = lane&15, quad = lane>>4;
  const int wm = (w>>1)*64, wn = (w&1)*64;
  f32x4 acc[4][4] = {};
  for (int k0 = 0; k0 < 256; k0 += 64) {
    if (k0) __syncthreads();
    #pragma unroll
    for (int pss = 0; pss < 4; ++pss) {
      int s = pss*256 + t;
      int row = s >> 3, pch = s & 7;
      int c = pch ^ (row & 7);              // XOR swizzle: phys chunk -> logical chunk
      const unsigned short* ga = X  + (size_t)(m0+row)*256 + k0 + c*8;
      const unsigned short* gb = Wt + (size_t)(n0+row)*256 + k0 + c*8;
      GLOAD_LDS16(ga, As + (s & ~63)*8);
      GLOAD_LDS16(gb, Bs + (s & ~63)*8);
    }
    __syncthreads();
    #pragma unroll
    for (int kt = 0; kt < 2; ++kt) {
      short8 af[4], bfr[4];
      #pragma unroll
      for (int mt=0;mt<4;++mt){ int r = wm+mt*16+fr; int ch = (kt*4+quad)^(r&7);
        af[mt] = *(const short8*)(As + r*64 + ch*8); }
      #pragma unroll
      for (int nt=0;nt<4;++nt){ int r = wn+nt*16+fr; int ch = (kt*4+quad)^(r&7);
        bfr[nt] = *(const short8*)(Bs + r*64 + ch*8); }
      #pragma unroll
      for (int mt=0;mt<4;++mt)
        #pragma unroll
        for (int nt=0;nt<4;++nt)
          acc[mt][nt] = mfma16(af[mt], bfr[nt], acc[mt][nt]);
    }
  }
  const int mat = n0 >> 8;   // uniform per block (128-col blocks)
  #pragma unroll
  for (int mt=0;mt<4;++mt) {
    #pragma unroll
    for (int nt=0;nt<4;++nt) {
      const int ng = n0 + wn + nt*16 + fr;
      const int h = (ng>>5)&7, d = ng&31;
      #pragma unroll
      for (int reg=0;reg<4;++reg) {
        const int m = m0 + wm + mt*16 + quad*4 + reg;
        float v = acc[mt][nt][reg];
        if (mat == 3) v = 1.f/(1.f + __expf(-(v + bg[ng&255])));
        const unsigned short bv = f2bf(v);
        if (mat == 2) {   // V: transposed + chunk-swizzled store
          const int ll = m>>7, nn = m&127;
          const int c = nn>>3, ph = c ^ (d&7);
          vT[((size_t)(h*1024 + ll))*4096 + d*128 + ph*8 + (nn&7)] = bv;
        } else {
          const int mi = ((mat==3)?2:mat)*8 + h;
          qkg[((size_t)mi*131072 + m)*32 + d] = bv;
        }
      }
    }
  }
}

// ---------------- kernel 5: MFMA attention, block = one l, 8 waves, heads serial ----------------
__global__ __launch_bounds__(512) void attn_mfma(
    const unsigned short* __restrict__ qkg, const unsigned short* __restrict__ vT,
    const float* __restrict__ biasb, unsigned short* __restrict__ attn)
{
  __shared__ __align__(16) unsigned short qs[128*32], ks[128*32], gs[128*32], vs[32*128];
  __shared__ __align__(16) unsigned short pbuf[8][16*136];
  const int t = threadIdx.x, l = blockIdx.x;
  const int w = t>>6, fr = t&15, quad = (t>>4)&3;
  unsigned short* pw = pbuf[w];
  const int rbase = w*16;
  const f32x4 zero4 = {0.f,0.f,0.f,0.f};
  for (int h = 0; h < 8; ++h) {
    {
      const unsigned short* g0 = qkg + ((size_t)(0*8+h)*131072 + (size_t)l*128)*32 + t*8;
      const unsigned short* g1 = qkg + ((size_t)(1*8+h)*131072 + (size_t)l*128)*32 + t*8;
      const unsigned short* g2 = qkg + ((size_t)(2*8+h)*131072 + (size_t)l*128)*32 + t*8;
      const unsigned short* g3 = vT  + ((size_t)(h*1024 + l))*4096 + t*8;
      const int lb = (t & ~63)*8;
      GLOAD_LDS16(g0, qs + lb);
      GLOAD_LDS16(g1, ks + lb);
      GLOAD_LDS16(g2, gs + lb);
      GLOAD_LDS16(g3, vs + lb);
    }
    __syncthreads();
    // QK^T : A = q rows [rbase..rbase+15], B = k rows (8 col-tiles)
    short8 aq = *(const short8*)(qs + (rbase+fr)*32 + quad*8);
    f32x4 S[8];
    #pragma unroll
    for (int nt=0;nt<8;++nt) {
      short8 bk = *(const short8*)(ks + (nt*16+fr)*32 + quad*8);
      S[nt] = mfma16(aq, bk, zero4);
    }
    // + pair bias (C layout: row = quad*4+reg, col = nt*16+fr)
    const float* bb = biasb + ((size_t)h*128 + rbase + quad*4)*128 + fr;
    #pragma unroll
    for (int nt=0;nt<8;++nt)
      #pragma unroll
      for (int reg=0;reg<4;++reg)
        S[nt][reg] += bb[(size_t)reg*128 + nt*16];
    // softmax over 128 cols: per-lane 8 tiles, then shfl over the 16-lane col group
    float mx[4] = {-1e30f,-1e30f,-1e30f,-1e30f};
    #pragma unroll
    for (int nt=0;nt<8;++nt)
      #pragma unroll
      for (int reg=0;reg<4;++reg) mx[reg] = fmaxf(mx[reg], S[nt][reg]);
    #pragma unroll
    for (int reg=0;reg<4;++reg) {
      mx[reg] = fmaxf(mx[reg], __shfl_xor(mx[reg], 1, 64));
      mx[reg] = fmaxf(mx[reg], __shfl_xor(mx[reg], 2, 64));
      mx[reg] = fmaxf(mx[reg], __shfl_xor(mx[reg], 4, 64));
      mx[reg] = fmaxf(mx[reg], __shfl_xor(mx[reg], 8, 64));
    }
    float sum[4] = {0.f,0.f,0.f,0.f};
    #pragma unroll
    for (int nt=0;nt<8;++nt)
      #pragma unroll
      for (int reg=0;reg<4;++reg) {
        float e = __expf(S[nt][reg]-mx[reg]);
        S[nt][reg] = e; sum[reg] += e;
      }
    #pragma unroll
    for (int reg=0;reg<4;++reg) {
      sum[reg] += __shfl_xor(sum[reg], 1, 64);
      sum[reg] += __shfl_xor(sum[reg], 2, 64);
      sum[reg] += __shfl_xor(sum[reg], 4, 64);
      sum[reg] += __shfl_xor(sum[reg], 8, 64);
    }
    float inv[4];
    #pragma unroll
    for (int reg=0;reg<4;++reg) inv[reg] = 1.f/sum[reg];
    // P -> per-wave LDS (C layout -> A layout), pitch 136
    #pragma unroll
    for (int nt=0;nt<8;++nt)
      #pragma unroll
      for (int reg=0;reg<4;++reg)
        pw[(quad*4+reg)*136 + nt*16 + fr] = f2bf(S[nt][reg]*inv[reg]);
    __builtin_amdgcn_s_waitcnt(0);   // wave-private LDS: drain ds writes before reads
    // PV : A = P[16][128], B = vT (chunk-swizzled)
    f32x4 o[2] = {zero4, zero4};
    #pragma unroll
    for (int kt=0;kt<4;++kt) {
      short8 ap = *(const short8*)(pw + fr*136 + kt*32 + quad*8);
      #pragma unroll
      for (int n2=0;n2<2;++n2) {
        const int d = n2*16 + fr;
        const int ph = (kt*4+quad) ^ (d&7);
        short8 bv = *(const short8*)(vs + d*128 + ph*8);
        o[n2] = mfma16(ap, bv, o[n2]);
      }
    }
    // gate + store (over dead x16 buffer)
    #pragma unroll
    for (int n2=0;n2<2;++n2)
      #pragma unroll
      for (int reg=0;reg<4;++reg) {
        const int row = rbase + quad*4 + reg, col = n2*16 + fr;
        const float gv = bf1(gs[row*32 + col]);
        attn[((size_t)l*128 + row)*256 + h*32 + col] = f2bf(o[n2][reg]*gv);
      }
    __syncthreads();
  }
}

// ---------------- kernel 6: out = attn @ Wo + bo, written transposed to [d_m][n][L] ----------------
__global__ __launch_bounds__(256) void outproj_kernel(
    const unsigned short* __restrict__ attn16, const float* __restrict__ Wo,
    const float* __restrict__ bo, float* __restrict__ out)
{
  __shared__ float As[16*68];
  __shared__ float Bs[16*68];
  const int t  = threadIdx.x;
  const int l0 = blockIdx.x * 64;
  const int c0 = blockIdx.y * 64;
  const int iz = blockIdx.z;
  const int tx = t & 15, ty = t >> 4;
  float acc[4][4];
  #pragma unroll
  for (int a=0;a<4;++a){
    #pragma unroll
    for (int b=0;b<4;++b) acc[a][b]=0.f;
  }
  for (int kc = 0; kc < 256; kc += 16) {
    if (kc) __syncthreads();
    {
      const int r = t >> 2, kq = (t & 3)*4;
      const unsigned short* src = attn16 + ((size_t)(l0+r)*128 + iz)*256 + kc + kq;
      uint2 u2 = *(const uint2*)src;
      As[(kq+0)*68 + r] = bf_lo(u2.x);
      As[(kq+1)*68 + r] = bf_hi(u2.x);
      As[(kq+2)*68 + r] = bf_lo(u2.y);
      As[(kq+3)*68 + r] = bf_hi(u2.y);
      const int kk = t >> 4, cq = (t & 15)*4;
      float4 wv = *(const float4*)(Wo + (size_t)(kc+kk)*256 + c0 + cq);
      *(float4*)&Bs[kk*68 + cq] = wv;
    }
    __syncthreads();
    #pragma unroll
    for (int kk=0; kk<16; ++kk) {
      float4 av = *(const float4*)&As[kk*68 + ty*4];
      float4 bv = *(const float4*)&Bs[kk*68 + tx*4];
      acc[0][0]+=av.x*bv.x; acc[0][1]+=av.x*bv.y; acc[0][2]+=av.x*bv.z; acc[0][3]+=av.x*bv.w;
      acc[1][0]+=av.y*bv.x; acc[1][1]+=av.y*bv.y; acc[1][2]+=av.y*bv.z; acc[1][3]+=av.y*bv.w;
      acc[2][0]+=av.z*bv.x; acc[2][1]+=av.z*bv.y; acc[2][2]+=av.z*bv.z; acc[2][3]+=av.z*bv.w;
      acc[3][0]+=av.w*bv.x; acc[3][1]+=av.w*bv.y; acc[3][2]+=av.w*bv.z; acc[3][3]+=av.w*bv.w;
    }
  }
  #pragma unroll
  for (int uc=0; uc<4; ++uc) {
    const int c = c0 + tx*4 + uc;
    const float bv = bo[c];
    float4 res;
    res.x = acc[0][uc] + bv;
    res.y = acc[1][uc] + bv;
    res.z = acc[2][uc] + bv;
    res.w = acc[3][uc] + bv;
    *(float4*)(out + (size_t)c*131072 + (size_t)iz*1024 + l0 + ty*4) = res;
  }
}

// ---------------- launch ----------------
extern "C" void kernel_launch(void* const* d_in, const int* in_sizes, int n_in,
                              void* d_out, int out_size, void* d_ws, size_t ws_size,
                              hipStream_t stream) {
  const float* msa    = (const float*)d_in[0];
  const float* pairs  = (const float*)d_in[1];
  const float* ln_m_g = (const float*)d_in[2];
  const float* ln_m_b = (const float*)d_in[3];
  const float* ln_p_g = (const float*)d_in[4];
  const float* ln_p_b = (const float*)d_in[5];
  const float* Wq     = (const float*)d_in[6];
  const float* Wk     = (const float*)d_in[7];
  const float* Wv     = (const float*)d_in[8];
  const float* Wg     = (const float*)d_in[9];
  const float* bg     = (const float*)d_in[10];
  const float* Wb     = (const float*)d_in[11];
  const float* Wo     = (const float*)d_in[12];
  const float* bo     = (const float*)d_in[13];
  float* out = (float*)d_out;

  // workspace layout (bytes):
  // qkg  @ 0          : 24 * 131072 * 32 * 2 = 192 MiB
  // vT   @ 192 MiB    : 8 * 1024 * 4096 * 2  = 64 MiB
  // x16  @ 256 MiB    : 131072 * 256 * 2     = 64 MiB (reused as attn output)
  // bias @ 320 MiB    : 8*128*128*4          = 512 KiB
  // Wt   @ 320.5 MiB  : 1024*256*2           = 512 KiB
  char* ws = (char*)d_ws;
  unsigned short* qkg  = (unsigned short*)(ws);
  unsigned short* vT   = (unsigned short*)(ws + (size_t)201326592);
  unsigned short* x16  = (unsigned short*)(ws + (size_t)268435456);
  float*          biasb= (float*)         (ws + (size_t)335544320);
  unsigned short* Wt   = (unsigned short*)(ws + (size_t)336068608);

  hipLaunchKernelGGL(ln_msa_kernel, dim3(32,128), dim3(256), 0, stream,
                     msa, ln_m_g, ln_m_b, x16);
  hipLaunchKernelGGL(pair_bias_kernel, dim3(128,128), dim3(64), 0, stream,
                     pairs, ln_p_g, ln_p_b, Wb, biasb);
  hipLaunchKernelGGL(wprep_kernel, dim3(1024), dim3(256), 0, stream,
                     Wq, Wk, Wv, Wg, Wt);
  hipLaunchKernelGGL(qkvg_gemm, dim3(1024,8), dim3(256), 0, stream,
                     x16, Wt, bg, qkg, vT);
  hipLaunchKernelGGL(attn_mfma, dim3(1024), dim3(512), 0, stream,
                     qkg, vT, biasb, x16);
  hipLaunchKernelGGL(outproj_kernel, dim3(16,4,128), dim3(256), 0, stream,
                     x16, Wo, bo, out);
}

// Round 3
// 634.111 us; speedup vs baseline: 4.5494x; 1.2421x over previous
//
#include <hip/hip_runtime.h>

// ---------------- helpers ----------------
__device__ __forceinline__ float bf_lo(unsigned u){ return __uint_as_float(u << 16); }
__device__ __forceinline__ float bf_hi(unsigned u){ return __uint_as_float(u & 0xffff0000u); }
__device__ __forceinline__ float bf1(unsigned short s){ return __uint_as_float((unsigned)s << 16); }
__device__ __forceinline__ unsigned short f2bf(float f){
  unsigned u = __float_as_uint(f);
  u += 0x7fffu + ((u >> 16) & 1u);   // RNE
  return (unsigned short)(u >> 16);
}

typedef __attribute__((ext_vector_type(8))) short short8;
typedef __attribute__((ext_vector_type(4))) float f32x4;

__device__ __forceinline__ f32x4 mfma16(short8 a, short8 b, f32x4 c){
  return __builtin_amdgcn_mfma_f32_16x16x32_bf16(a, b, c, 0, 0, 0);
}

#define GLOAD_LDS16(g, l) \
  __builtin_amdgcn_global_load_lds((const __attribute__((address_space(1))) unsigned int*)(g), \
                                   (__attribute__((address_space(3))) unsigned int*)(l), 16, 0, 0)

// ---------------- kernel 1: LayerNorm over d_m + transpose msa[c][n][l] -> x[l][n][c] (bf16) ----------------
__global__ __launch_bounds__(256) void ln_msa_kernel(
    const float* __restrict__ msa, const float* __restrict__ gam,
    const float* __restrict__ bet, unsigned short* __restrict__ x16)
{
  __shared__ float tile[256*33];          // [c][l] pitch 33
  __shared__ float ps[8*32], pq[8*32];
  __shared__ float mean_s[32], rstd_s[32];
  const int t = threadIdx.x;
  const int l0 = blockIdx.x * 32;
  const int n  = blockIdx.y;
  {
    const int lt = t & 31, ct = t >> 5;
    for (int r = 0; r < 32; ++r) {
      int c = r*8 + ct;
      tile[c*33 + lt] = msa[(size_t)c*131072 + (size_t)n*1024 + l0 + lt];
    }
  }
  __syncthreads();
  {
    const int lt = t & 31, cp = t >> 5;
    float s1 = 0.f, s2 = 0.f;
    for (int cc = 0; cc < 32; ++cc) {
      int c = cp*32 + ((cc + cp*4) & 31);
      float v = tile[c*33 + lt];
      s1 += v; s2 += v*v;
    }
    ps[cp*32 + lt] = s1; pq[cp*32 + lt] = s2;
  }
  __syncthreads();
  if (t < 32) {
    float s1 = 0.f, s2 = 0.f;
    for (int cp = 0; cp < 8; ++cp){ s1 += ps[cp*32+t]; s2 += pq[cp*32+t]; }
    float m = s1 * (1.f/256.f);
    float v = s2 * (1.f/256.f) - m*m;
    mean_s[t] = m;
    rstd_s[t] = rsqrtf(v + 1e-5f);
  }
  __syncthreads();
  {
    const float g = gam[t], b = bet[t];
    for (int l = 0; l < 32; ++l) {
      float v = (tile[t*33 + l] - mean_s[l]) * rstd_s[l] * g + b;
      x16[((size_t)(l0+l)*128 + n)*256 + t] = f2bf(v);
    }
  }
}

// ---------------- kernel 2: pair bias = LN(pairs) @ Wb -> bias[h][i][j] fp32 ----------------
__global__ __launch_bounds__(64) void pair_bias_kernel(
    const float* __restrict__ pairs, const float* __restrict__ gam,
    const float* __restrict__ bet, const float* __restrict__ Wb,
    float* __restrict__ biasb)
{
  const int j = blockIdx.x, i = blockIdx.y;
  const int t = threadIdx.x;
  const float* row = pairs + ((size_t)i*128 + j)*128;
  float v0 = row[t], v1 = row[t+64];
  float s = v0 + v1;
  #pragma unroll
  for (int o = 1; o < 64; o <<= 1) s += __shfl_xor(s, o, 64);
  float m = s * (1.f/128.f);
  float d0 = v0 - m, d1 = v1 - m;
  float q = d0*d0 + d1*d1;
  #pragma unroll
  for (int o = 1; o < 64; o <<= 1) q += __shfl_xor(q, o, 64);
  float rstd = rsqrtf(q * (1.f/128.f) + 1e-5f);
  float n0 = d0 * rstd * gam[t]    + bet[t];
  float n1 = d1 * rstd * gam[t+64] + bet[t+64];
  #pragma unroll
  for (int h = 0; h < 8; ++h) {
    float p = n0 * Wb[t*8 + h] + n1 * Wb[(t+64)*8 + h];
    #pragma unroll
    for (int o = 1; o < 64; o <<= 1) p += __shfl_xor(p, o, 64);
    if (t == h) biasb[((size_t)h*128 + i)*128 + j] = p;
  }
}

// ---------------- kernel 3: weight prep ----------------
// n<1024: Wt[n][k] = W_mat[k][n&255] bf16 (q scaled by 1/sqrt(32))
// n>=1024: WoT[c][k] = Wo[k][c] bf16
__global__ __launch_bounds__(256) void wprep_kernel(
    const float* __restrict__ Wq, const float* __restrict__ Wk,
    const float* __restrict__ Wv, const float* __restrict__ Wg,
    const float* __restrict__ Wo,
    unsigned short* __restrict__ Wt, unsigned short* __restrict__ WoT)
{
  const int n = blockIdx.x, k = threadIdx.x;
  if (n < 1024) {
    const int mat = n >> 8, nl = n & 255;
    const float* W = (mat==0) ? Wq : (mat==1) ? Wk : (mat==2) ? Wv : Wg;
    float v = W[(size_t)k*256 + nl];
    if (mat == 0) v *= 0.17677669529663689f;   // 1/sqrt(32) folded into Wq
    Wt[(size_t)n*256 + k] = f2bf(v);
  } else {
    const int c = n - 1024;
    WoT[(size_t)c*256 + k] = f2bf(Wo[(size_t)k*256 + c]);
  }
}

// ---------------- kernel 4: MFMA GEMM: [Q|K|V|G] = X @ Wt^T ----------------
__global__ __launch_bounds__(256) void qkvg_gemm(
    const unsigned short* __restrict__ X, const unsigned short* __restrict__ Wt,
    const float* __restrict__ bg, unsigned short* __restrict__ qkg,
    unsigned short* __restrict__ vT)
{
  __shared__ __align__(16) unsigned short As[128*64], Bs[128*64];
  const int t = threadIdx.x;
  const int m0 = blockIdx.x*128, n0 = blockIdx.y*128;
  const int w = t>>6, lane = t&63, fr = lane&15, quad = lane>>4;
  const int wm = (w>>1)*64, wn = (w&1)*64;
  f32x4 acc[4][4] = {};
  for (int k0 = 0; k0 < 256; k0 += 64) {
    if (k0) __syncthreads();
    #pragma unroll
    for (int pss = 0; pss < 4; ++pss) {
      int s = pss*256 + t;
      int row = s >> 3, pch = s & 7;
      int c = pch ^ (row & 7);              // XOR swizzle
      const unsigned short* ga = X  + (size_t)(m0+row)*256 + k0 + c*8;
      const unsigned short* gb = Wt + (size_t)(n0+row)*256 + k0 + c*8;
      GLOAD_LDS16(ga, As + (s & ~63)*8);
      GLOAD_LDS16(gb, Bs + (s & ~63)*8);
    }
    __syncthreads();
    #pragma unroll
    for (int kt = 0; kt < 2; ++kt) {
      short8 af[4], bfr[4];
      #pragma unroll
      for (int mt=0;mt<4;++mt){ int r = wm+mt*16+fr; int ch = (kt*4+quad)^(r&7);
        af[mt] = *(const short8*)(As + r*64 + ch*8); }
      #pragma unroll
      for (int nt=0;nt<4;++nt){ int r = wn+nt*16+fr; int ch = (kt*4+quad)^(r&7);
        bfr[nt] = *(const short8*)(Bs + r*64 + ch*8); }
      #pragma unroll
      for (int mt=0;mt<4;++mt)
        #pragma unroll
        for (int nt=0;nt<4;++nt)
          acc[mt][nt] = mfma16(af[mt], bfr[nt], acc[mt][nt]);
    }
  }
  const int mat = n0 >> 8;
  #pragma unroll
  for (int mt=0;mt<4;++mt) {
    #pragma unroll
    for (int nt=0;nt<4;++nt) {
      const int ng = n0 + wn + nt*16 + fr;
      const int h = (ng>>5)&7, d = ng&31;
      #pragma unroll
      for (int reg=0;reg<4;++reg) {
        const int m = m0 + wm + mt*16 + quad*4 + reg;
        float v = acc[mt][nt][reg];
        if (mat == 3) v = 1.f/(1.f + __expf(-(v + bg[ng&255])));
        const unsigned short bv = f2bf(v);
        if (mat == 2) {   // V: transposed + chunk-swizzled store
          const int ll = m>>7, nn = m&127;
          const int c = nn>>3, ph = c ^ (d&7);
          vT[((size_t)(h*1024 + ll))*4096 + d*128 + ph*8 + (nn&7)] = bv;
        } else {
          const int mi = ((mat==3)?2:mat)*8 + h;
          qkg[((size_t)mi*131072 + m)*32 + d] = bv;
        }
      }
    }
  }
}

// ---------------- kernel 5: MFMA attention, block = one l, 8 waves, heads serial ----------------
// Output layout: attn2[n][l][c]  (n-major so outproj rows are contiguous)
__global__ __launch_bounds__(512) void attn_mfma(
    const unsigned short* __restrict__ qkg, const unsigned short* __restrict__ vT,
    const float* __restrict__ biasb, unsigned short* __restrict__ attn2)
{
  __shared__ __align__(16) unsigned short qs[128*32], ks[128*32], gs[128*32], vs[32*128];
  __shared__ __align__(16) unsigned short pbuf[8][16*136];
  const int t = threadIdx.x, l = blockIdx.x;
  const int w = t>>6, fr = t&15, quad = (t>>4)&3;
  unsigned short* pw = pbuf[w];
  const int rbase = w*16;
  const f32x4 zero4 = {0.f,0.f,0.f,0.f};
  for (int h = 0; h < 8; ++h) {
    {
      const unsigned short* g0 = qkg + ((size_t)(0*8+h)*131072 + (size_t)l*128)*32 + t*8;
      const unsigned short* g1 = qkg + ((size_t)(1*8+h)*131072 + (size_t)l*128)*32 + t*8;
      const unsigned short* g2 = qkg + ((size_t)(2*8+h)*131072 + (size_t)l*128)*32 + t*8;
      const unsigned short* g3 = vT  + ((size_t)(h*1024 + l))*4096 + t*8;
      const int lb = (t & ~63)*8;
      GLOAD_LDS16(g0, qs + lb);
      GLOAD_LDS16(g1, ks + lb);
      GLOAD_LDS16(g2, gs + lb);
      GLOAD_LDS16(g3, vs + lb);
    }
    __syncthreads();
    short8 aq = *(const short8*)(qs + (rbase+fr)*32 + quad*8);
    f32x4 S[8];
    #pragma unroll
    for (int nt=0;nt<8;++nt) {
      short8 bk = *(const short8*)(ks + (nt*16+fr)*32 + quad*8);
      S[nt] = mfma16(aq, bk, zero4);
    }
    const float* bb = biasb + ((size_t)h*128 + rbase + quad*4)*128 + fr;
    #pragma unroll
    for (int nt=0;nt<8;++nt)
      #pragma unroll
      for (int reg=0;reg<4;++reg)
        S[nt][reg] += bb[(size_t)reg*128 + nt*16];
    float mx[4] = {-1e30f,-1e30f,-1e30f,-1e30f};
    #pragma unroll
    for (int nt=0;nt<8;++nt)
      #pragma unroll
      for (int reg=0;reg<4;++reg) mx[reg] = fmaxf(mx[reg], S[nt][reg]);
    #pragma unroll
    for (int reg=0;reg<4;++reg) {
      mx[reg] = fmaxf(mx[reg], __shfl_xor(mx[reg], 1, 64));
      mx[reg] = fmaxf(mx[reg], __shfl_xor(mx[reg], 2, 64));
      mx[reg] = fmaxf(mx[reg], __shfl_xor(mx[reg], 4, 64));
      mx[reg] = fmaxf(mx[reg], __shfl_xor(mx[reg], 8, 64));
    }
    float sum[4] = {0.f,0.f,0.f,0.f};
    #pragma unroll
    for (int nt=0;nt<8;++nt)
      #pragma unroll
      for (int reg=0;reg<4;++reg) {
        float e = __expf(S[nt][reg]-mx[reg]);
        S[nt][reg] = e; sum[reg] += e;
      }
    #pragma unroll
    for (int reg=0;reg<4;++reg) {
      sum[reg] += __shfl_xor(sum[reg], 1, 64);
      sum[reg] += __shfl_xor(sum[reg], 2, 64);
      sum[reg] += __shfl_xor(sum[reg], 4, 64);
      sum[reg] += __shfl_xor(sum[reg], 8, 64);
    }
    float inv[4];
    #pragma unroll
    for (int reg=0;reg<4;++reg) inv[reg] = 1.f/sum[reg];
    #pragma unroll
    for (int nt=0;nt<8;++nt)
      #pragma unroll
      for (int reg=0;reg<4;++reg)
        pw[(quad*4+reg)*136 + nt*16 + fr] = f2bf(S[nt][reg]*inv[reg]);
    __builtin_amdgcn_s_waitcnt(0);   // wave-private LDS region
    f32x4 o[2] = {zero4, zero4};
    #pragma unroll
    for (int kt=0;kt<4;++kt) {
      short8 ap = *(const short8*)(pw + fr*136 + kt*32 + quad*8);
      #pragma unroll
      for (int n2=0;n2<2;++n2) {
        const int d = n2*16 + fr;
        const int ph = (kt*4+quad) ^ (d&7);
        short8 bv = *(const short8*)(vs + d*128 + ph*8);
        o[n2] = mfma16(ap, bv, o[n2]);
      }
    }
    #pragma unroll
    for (int n2=0;n2<2;++n2)
      #pragma unroll
      for (int reg=0;reg<4;++reg) {
        const int row = rbase + quad*4 + reg, col = n2*16 + fr;
        const float gv = bf1(gs[row*32 + col]);
        attn2[((size_t)row*1024 + l)*256 + h*32 + col] = f2bf(o[n2][reg]*gv);
      }
    __syncthreads();
  }
}

// ---------------- kernel 6: MFMA outproj: out[c][n][l] = Σ_k WoT[c][k]·attn2[n][l][k] + bo[c] ----------------
__global__ __launch_bounds__(256) void outproj_mfma(
    const unsigned short* __restrict__ attn2, const unsigned short* __restrict__ WoT,
    const float* __restrict__ bo, float* __restrict__ out)
{
  __shared__ __align__(16) unsigned short As[128*64], Bs[128*64];
  const int t = threadIdx.x;
  const int c0 = blockIdx.x*128;      // 2 tiles over d_m
  const int l0 = blockIdx.y*128;      // 8 tiles over L
  const int n  = blockIdx.z;          // 128
  const int w = t>>6, lane = t&63, fr = lane&15, quad = lane>>4;
  const int wm = (w>>1)*64, wn = (w&1)*64;
  f32x4 acc[4][4] = {};
  for (int k0 = 0; k0 < 256; k0 += 64) {
    if (k0) __syncthreads();
    #pragma unroll
    for (int pss = 0; pss < 4; ++pss) {
      int s = pss*256 + t;
      int row = s >> 3, pch = s & 7;
      int c = pch ^ (row & 7);
      const unsigned short* ga = WoT   + (size_t)(c0+row)*256 + k0 + c*8;
      const unsigned short* gb = attn2 + ((size_t)n*1024 + l0 + row)*256 + k0 + c*8;
      GLOAD_LDS16(ga, As + (s & ~63)*8);
      GLOAD_LDS16(gb, Bs + (s & ~63)*8);
    }
    __syncthreads();
    #pragma unroll
    for (int kt = 0; kt < 2; ++kt) {
      short8 af[4], bfr[4];
      #pragma unroll
      for (int mt=0;mt<4;++mt){ int r = wm+mt*16+fr; int ch = (kt*4+quad)^(r&7);
        af[mt] = *(const short8*)(As + r*64 + ch*8); }
      #pragma unroll
      for (int nt=0;nt<4;++nt){ int r = wn+nt*16+fr; int ch = (kt*4+quad)^(r&7);
        bfr[nt] = *(const short8*)(Bs + r*64 + ch*8); }
      #pragma unroll
      for (int mt=0;mt<4;++mt)
        #pragma unroll
        for (int nt=0;nt<4;++nt)
          acc[mt][nt] = mfma16(af[mt], bfr[nt], acc[mt][nt]);
    }
  }
  #pragma unroll
  for (int mt=0;mt<4;++mt) {
    #pragma unroll
    for (int reg=0;reg<4;++reg) {
      const int c = c0 + wm + mt*16 + quad*4 + reg;
      const float bv = bo[c];
      #pragma unroll
      for (int nt=0;nt<4;++nt) {
        const int l = l0 + wn + nt*16 + fr;
        out[(size_t)c*131072 + (size_t)n*1024 + l] = acc[mt][nt][reg] + bv;
      }
    }
  }
}

// ---------------- launch ----------------
extern "C" void kernel_launch(void* const* d_in, const int* in_sizes, int n_in,
                              void* d_out, int out_size, void* d_ws, size_t ws_size,
                              hipStream_t stream) {
  const float* msa    = (const float*)d_in[0];
  const float* pairs  = (const float*)d_in[1];
  const float* ln_m_g = (const float*)d_in[2];
  const float* ln_m_b = (const float*)d_in[3];
  const float* ln_p_g = (const float*)d_in[4];
  const float* ln_p_b = (const float*)d_in[5];
  const float* Wq     = (const float*)d_in[6];
  const float* Wk     = (const float*)d_in[7];
  const float* Wv     = (const float*)d_in[8];
  const float* Wg     = (const float*)d_in[9];
  const float* bg     = (const float*)d_in[10];
  const float* Wb     = (const float*)d_in[11];
  const float* Wo     = (const float*)d_in[12];
  const float* bo     = (const float*)d_in[13];
  float* out = (float*)d_out;

  // workspace layout (bytes):
  // qkg  @ 0          : 24 * 131072 * 32 * 2 = 192 MiB
  // vT   @ 192 MiB    : 8 * 1024 * 4096 * 2  = 64 MiB
  // x16  @ 256 MiB    : 131072 * 256 * 2     = 64 MiB (reused as attn2 [n][l][c])
  // bias @ 320 MiB    : 8*128*128*4          = 512 KiB
  // Wt   @ 320.5 MiB  : 1024*256*2           = 512 KiB
  // WoT  @ 321 MiB    : 256*256*2            = 128 KiB
  char* ws = (char*)d_ws;
  unsigned short* qkg  = (unsigned short*)(ws);
  unsigned short* vT   = (unsigned short*)(ws + (size_t)201326592);
  unsigned short* x16  = (unsigned short*)(ws + (size_t)268435456);
  float*          biasb= (float*)         (ws + (size_t)335544320);
  unsigned short* Wt   = (unsigned short*)(ws + (size_t)336068608);
  unsigned short* WoT  = (unsigned short*)(ws + (size_t)336592896);

  hipLaunchKernelGGL(ln_msa_kernel, dim3(32,128), dim3(256), 0, stream,
                     msa, ln_m_g, ln_m_b, x16);
  hipLaunchKernelGGL(pair_bias_kernel, dim3(128,128), dim3(64), 0, stream,
                     pairs, ln_p_g, ln_p_b, Wb, biasb);
  hipLaunchKernelGGL(wprep_kernel, dim3(1280), dim3(256), 0, stream,
                     Wq, Wk, Wv, Wg, Wo, Wt, WoT);
  hipLaunchKernelGGL(qkvg_gemm, dim3(1024,8), dim3(256), 0, stream,
                     x16, Wt, bg, qkg, vT);
  hipLaunchKernelGGL(attn_mfma, dim3(1024), dim3(512), 0, stream,
                     qkg, vT, biasb, x16);
  hipLaunchKernelGGL(outproj_mfma, dim3(2,8,128), dim3(256), 0, stream,
                     x16, WoT, bo, out);
}